// Round 1
// baseline (247.195 us; speedup 1.0000x reference)
//
#include <hip/hip_runtime.h>
#include <stdint.h>
#include <stddef.h>

// Problem constants (compile-time, from reference)
#define B_ 4
#define T_ 1024
#define C_ 768
#define H_ 12
// HD = 64, WIN = 4 -> band r in [0,9), j - i = r - 3

typedef __attribute__((ext_vector_type(4))) float f32x4;
typedef __attribute__((ext_vector_type(8))) short s16x8;
typedef __attribute__((ext_vector_type(4))) float float4v;

typedef const __attribute__((address_space(1))) uint32_t ga_u32;
typedef __attribute__((address_space(3))) uint32_t lds_u32;

__device__ __forceinline__ float bf2f(uint16_t u) {
    union { uint32_t u; float f; } cv; cv.u = ((uint32_t)u) << 16; return cv.f;
}
__device__ __forceinline__ uint16_t f2bf(float f) {
    union { float f; uint32_t u; } cv; cv.f = f;
    uint32_t u = cv.u;
    return (uint16_t)((u + 0x7FFFu + ((u >> 16) & 1u)) >> 16);
}
__device__ __forceinline__ void gload16(const uint16_t* g, uint16_t* l) {
    // async global->LDS, 16B per lane; LDS dest must be linear (base + lane*16)
    __builtin_amdgcn_global_load_lds((ga_u32*)g, (lds_u32*)l, 16, 0, 0);
}

// ---------------------------------------------------------------------------
// K0a: transpose+convert x,c (b,C,T) f32 -> xT,cT (b,T,C) bf16
// ---------------------------------------------------------------------------
__global__ void transpose_bf16_kernel(const float* __restrict__ x,
                                      const float* __restrict__ c,
                                      uint16_t* __restrict__ xT,
                                      uint16_t* __restrict__ cT) {
    __shared__ float tile[32][33];
    const int which = blockIdx.z;            // 0: x, 1: c
    const int b = blockIdx.y;
    const int t0 = (blockIdx.x % (T_ / 32)) * 32;
    const int c0 = (blockIdx.x / (T_ / 32)) * 32;
    const float* src = (which ? c : x) + (size_t)b * C_ * T_;
    uint16_t* dst = (which ? cT : xT) + (size_t)b * T_ * C_;
    const int lj = threadIdx.x & 31, li = threadIdx.x >> 5;  // 256 thr: li 0..7
    #pragma unroll
    for (int i = li; i < 32; i += 8)
        tile[i][lj] = src[(size_t)(c0 + i) * T_ + t0 + lj];
    __syncthreads();
    #pragma unroll
    for (int i = li; i < 32; i += 8)
        dst[(size_t)(t0 + i) * C_ + c0 + lj] = f2bf(tile[lj][i]);
}

// ---------------------------------------------------------------------------
// K0b: convert 4 weight matrices (768x768 f32, row-major (o,c)) to bf16 concat
// ---------------------------------------------------------------------------
__global__ void convert_weights_kernel(const float* __restrict__ wq,
                                       const float* __restrict__ wk,
                                       const float* __restrict__ wv,
                                       const float* __restrict__ wo,
                                       uint16_t* __restrict__ out) {
    const int which = blockIdx.y;
    const float* w = (which == 0) ? wq : (which == 1) ? wk : (which == 2) ? wv : wo;
    uint16_t* dst = out + (size_t)which * C_ * C_;
    const int i = (blockIdx.x * 256 + threadIdx.x) * 4;   // C*C = 589824 = 576*256*4
    float4v v = *(const float4v*)(w + i);
    uint32_t lo = (uint32_t)f2bf(v[0]) | ((uint32_t)f2bf(v[1]) << 16);
    uint32_t hi = (uint32_t)f2bf(v[2]) | ((uint32_t)f2bf(v[3]) << 16);
    uint32_t* d32 = (uint32_t*)(dst + i);
    d32[0] = lo; d32[1] = hi;
}

// ---------------------------------------------------------------------------
// K0c: mask (B,1,T,T) f32 -> bitmask, bit=1 where mask != 0
// ---------------------------------------------------------------------------
__global__ void mask_bits_kernel(const float* __restrict__ mask,
                                 uint32_t* __restrict__ bits) {
    const size_t i = (size_t)blockIdx.x * 256 + threadIdx.x;   // total B*T*T
    const float m = mask[i];
    unsigned long long bal = __ballot(m != 0.0f);
    const int lane = threadIdx.x & 63;
    if (lane == 0)       bits[i >> 5] = (uint32_t)bal;
    else if (lane == 32) bits[i >> 5] = (uint32_t)(bal >> 32);
}

// ---------------------------------------------------------------------------
// GEMM: C[m][n] = sum_k A[m][k]*B[n][k] (+bias), K=768, lda=ldb=768.
// 128x128 tile, BK=64, 4 waves (2x2), 16x16x32 bf16 MFMA,
// global_load_lds staging with source-side XOR swizzle (rule #21).
// OPROJ=false: z in [0,12): which=z>>2 (0:Q 1:K 2:V), bat=z&3
// OPROJ=true : z = batch, final output (f32) to d_out
// ---------------------------------------------------------------------------
template <bool OPROJ>
__global__ __launch_bounds__(256, 2)
void gemm_kernel(const uint16_t* __restrict__ xT, const uint16_t* __restrict__ cT,
                 const uint16_t* __restrict__ wb,
                 const float* __restrict__ bq, const float* __restrict__ bk,
                 const float* __restrict__ bv, const float* __restrict__ bo,
                 const uint16_t* __restrict__ attT,
                 uint16_t* __restrict__ Qb, uint16_t* __restrict__ Kb,
                 uint16_t* __restrict__ Vb, float* __restrict__ outp) {
    const int tid = threadIdx.x;
    const int z = blockIdx.z;

    const uint16_t* A; const uint16_t* Bm; const float* bias;
    uint16_t* Cb = nullptr; float* Cf = nullptr;
    int N, ldc; bool bias_col;
    if (!OPROJ) {
        const int bat = z & 3, which = z >> 2;
        if (which == 0) {
            A = xT + (size_t)bat * T_ * C_; Bm = wb;                bias = bq;
            Cb = Qb + (size_t)bat * T_ * C_; N = C_; ldc = C_; bias_col = true;
        } else if (which == 1) {
            A = cT + (size_t)bat * T_ * C_; Bm = wb + 1 * C_ * C_;  bias = bk;
            Cb = Kb + (size_t)bat * T_ * C_; N = C_; ldc = C_; bias_col = true;
        } else {
            A = wb + 2 * (size_t)C_ * C_;   Bm = cT + (size_t)(z & 3) * T_ * C_; bias = bv;
            Cb = Vb + (size_t)bat * C_ * T_; N = T_; ldc = T_; bias_col = false;
        }
    } else {
        A = wb + 3 * (size_t)C_ * C_; Bm = attT + (size_t)z * T_ * C_; bias = bo;
        Cf = outp + (size_t)z * C_ * T_; N = T_; ldc = T_; bias_col = false;
    }
    const int tn_cnt = N / 128;
    const int tm = blockIdx.x / tn_cnt, tn = blockIdx.x % tn_cnt;
    const int row0 = tm * 128, col0 = tn * 128;

    __shared__ uint16_t As[128 * 64];
    __shared__ uint16_t Bs[128 * 64];

    const int w = tid >> 6, l = tid & 63;
    const int wr = w & 1, wc = w >> 1;

    const f32x4 zz = {0.f, 0.f, 0.f, 0.f};
    f32x4 acc[4][4];
    #pragma unroll
    for (int i = 0; i < 4; ++i)
        #pragma unroll
        for (int j = 0; j < 4; ++j) acc[i][j] = zz;

    const int sr = tid >> 3, sp = tid & 7;

    for (int kt = 0; kt < 12; ++kt) {
        const int k0 = kt * 64;
        #pragma unroll
        for (int it = 0; it < 4; ++it) {
            const int row = it * 32 + sr;
            const int cch = sp ^ (row & 7);
            gload16(A + (size_t)(row0 + row) * 768 + k0 + cch * 8, &As[row * 64 + sp * 8]);
        }
        #pragma unroll
        for (int it = 0; it < 4; ++it) {
            const int row = it * 32 + sr;
            const int cch = sp ^ (row & 7);
            gload16(Bm + (size_t)(col0 + row) * 768 + k0 + cch * 8, &Bs[row * 64 + sp * 8]);
        }
        __syncthreads();   // compiler drains vmcnt before barrier

        #pragma unroll
        for (int kk = 0; kk < 2; ++kk) {
            s16x8 af[4], bf[4];
            #pragma unroll
            for (int i = 0; i < 4; ++i) {
                const int arow = wr * 64 + i * 16 + (l & 15);
                const int ach = (kk * 4 + (l >> 4)) ^ (arow & 7);
                af[i] = *(const s16x8*)(&As[arow * 64 + ach * 8]);
                const int brow = wc * 64 + i * 16 + (l & 15);
                const int bch = (kk * 4 + (l >> 4)) ^ (brow & 7);
                bf[i] = *(const s16x8*)(&Bs[brow * 64 + bch * 8]);
            }
            #pragma unroll
            for (int i = 0; i < 4; ++i)
                #pragma unroll
                for (int j = 0; j < 4; ++j)
                    acc[i][j] = __builtin_amdgcn_mfma_f32_16x16x32_bf16(af[i], bf[j], acc[i][j], 0, 0, 0);
        }
        __syncthreads();
    }

    // epilogue: D row=(l>>4)*4+reg, col=l&15 per 16x16 tile
    #pragma unroll
    for (int i = 0; i < 4; ++i) {
        const int rowb = row0 + wr * 64 + i * 16 + ((l >> 4) * 4);
        #pragma unroll
        for (int j = 0; j < 4; ++j) {
            const int col = col0 + wc * 64 + j * 16 + (l & 15);
            const float bc = bias_col ? bias[col] : 0.f;
            #pragma unroll
            for (int r = 0; r < 4; ++r) {
                const int row = rowb + r;
                const float v = acc[i][j][r] + (bias_col ? bc : bias[row]);
                if (!OPROJ) Cb[(size_t)row * ldc + col] = f2bf(v);
                else        Cf[(size_t)row * ldc + col] = v;
            }
        }
    }
}

// ---------------------------------------------------------------------------
// Attention: grid (T/64, H, B), 256 thr = 4 waves, each wave owns 16 q-rows.
// Online softmax over KV tiles of 64. Band rel-k added on the fly; band scores
// captured for the rel-v epilogue term.
// ---------------------------------------------------------------------------
__global__ __launch_bounds__(256, 2)
void attn_kernel(const uint16_t* __restrict__ Qb, const uint16_t* __restrict__ Kb,
                 const uint16_t* __restrict__ Vb, const uint32_t* __restrict__ mbits,
                 const float* __restrict__ emb_k, const float* __restrict__ emb_v,
                 uint16_t* __restrict__ attT) {
    const int i0 = blockIdx.x * 64;
    const int h = blockIdx.y, b = blockIdx.z;
    const int tid = threadIdx.x, w = tid >> 6, l = tid & 63;
    const float scale = 0.125f;   // HD^-0.5

    __shared__ uint16_t Ks[64 * 64];   // swizzled rows j x c
    __shared__ uint16_t Vs[64 * 64];   // swizzled rows d x j
    __shared__ uint16_t Ps[64 * 72];   // padded, rows (block q-row) x j
    __shared__ float rk[64 * 9];       // scale * q_i . emb_rel_k[h,r,:]
    __shared__ float sband[64 * 9];    // captured masked band scores

    // Q fragments (held in registers for the whole kernel)
    s16x8 qf[2];
    {
        const int row = i0 + w * 16 + (l & 15);
        const uint16_t* qp = Qb + ((size_t)(b * T_ + row)) * C_ + h * 64 + (l >> 4) * 8;
        qf[0] = *(const s16x8*)(qp);
        qf[1] = *(const s16x8*)(qp + 32);
    }
    // rk + sband init
    for (int t = tid; t < 64 * 9; t += 256) {
        const int rr = t % 9, row = t / 9;
        const uint16_t* qp = Qb + ((size_t)(b * T_ + i0 + row)) * C_ + h * 64;
        const float* ep = emb_k + ((size_t)h * 9 + rr) * 64;
        float s = 0.f;
        #pragma unroll
        for (int d = 0; d < 64; ++d) s += bf2f(qp[d]) * ep[d];
        rk[t] = s * scale;
        sband[t] = -1e30f;
    }
    __syncthreads();

    float m[4], lsum[4];
    const f32x4 zz = {0.f, 0.f, 0.f, 0.f};
    f32x4 oacc[4] = {zz, zz, zz, zz};
    #pragma unroll
    for (int r = 0; r < 4; ++r) { m[r] = -1e30f; lsum[r] = 0.f; }

    const uint16_t* Kbase = Kb + (size_t)b * T_ * C_ + h * 64;
    const uint16_t* Vbase = Vb + (size_t)b * C_ * T_ + (size_t)(h * 64) * T_;
    const uint32_t* mrow = mbits + (size_t)b * T_ * 32;
    const int sr = tid >> 3, sp = tid & 7;

    for (int jt = 0; jt < 16; ++jt) {
        const int j0 = jt * 64;
        #pragma unroll
        for (int it = 0; it < 2; ++it) {
            const int row = it * 32 + sr;
            const int cch = sp ^ (row & 7);
            gload16(Kbase + (size_t)(j0 + row) * C_ + cch * 8, &Ks[row * 64 + sp * 8]);
        }
        #pragma unroll
        for (int it = 0; it < 2; ++it) {
            const int row = it * 32 + sr;                  // d index
            const int cch = sp ^ (row & 7);
            gload16(Vbase + (size_t)row * T_ + j0 + cch * 8, &Vs[row * 64 + sp * 8]);
        }
        __syncthreads();

        // S = Q K^T  (A=q rows, B=k rows)
        float sv[4][4];
        #pragma unroll
        for (int tn = 0; tn < 4; ++tn) {
            f32x4 s = zz;
            #pragma unroll
            for (int kk = 0; kk < 2; ++kk) {
                const int krow = tn * 16 + (l & 15);
                const int kch = (kk * 4 + (l >> 4)) ^ (krow & 7);
                s16x8 kf = *(const s16x8*)(&Ks[krow * 64 + kch * 8]);
                s = __builtin_amdgcn_mfma_f32_16x16x32_bf16(qf[kk], kf, s, 0, 0, 0);
            }
            #pragma unroll
            for (int r = 0; r < 4; ++r) {
                const int iloc = w * 16 + (l >> 4) * 4 + r;  // block-local q row
                const int i = i0 + iloc;
                const int j = j0 + tn * 16 + (l & 15);
                float sc = s[r] * scale;
                const int rr = j - i + 3;
                const bool band = (rr >= 0) && (rr < 9);
                if (band) sc += rk[iloc * 9 + rr];
                const uint32_t mw = mrow[(size_t)i * 32 + (j >> 5)];
                if (!((mw >> (j & 31)) & 1u)) sc = -1e4f;
                if (band) sband[iloc * 9 + rr] = sc;
                sv[tn][r] = sc;
            }
        }

        // online softmax (rows live in 16-lane groups; shfl_xor 1,2,4,8)
        #pragma unroll
        for (int r = 0; r < 4; ++r) {
            float rm = fmaxf(fmaxf(sv[0][r], sv[1][r]), fmaxf(sv[2][r], sv[3][r]));
            rm = fmaxf(rm, __shfl_xor(rm, 1));
            rm = fmaxf(rm, __shfl_xor(rm, 2));
            rm = fmaxf(rm, __shfl_xor(rm, 4));
            rm = fmaxf(rm, __shfl_xor(rm, 8));
            const float mn = fmaxf(m[r], rm);
            const float alpha = __expf(m[r] - mn);
            m[r] = mn;
            float rs = 0.f;
            #pragma unroll
            for (int tn = 0; tn < 4; ++tn) {
                const float p = __expf(sv[tn][r] - mn);
                sv[tn][r] = p;
                rs += p;
            }
            rs += __shfl_xor(rs, 1);
            rs += __shfl_xor(rs, 2);
            rs += __shfl_xor(rs, 4);
            rs += __shfl_xor(rs, 8);
            lsum[r] = lsum[r] * alpha + rs;
            #pragma unroll
            for (int td = 0; td < 4; ++td) oacc[td][r] *= alpha;
        }

        // P -> LDS (bf16), padded stride 72 to avoid bank conflicts
        #pragma unroll
        for (int tn = 0; tn < 4; ++tn)
            #pragma unroll
            for (int r = 0; r < 4; ++r) {
                const int prow = w * 16 + (l >> 4) * 4 + r;
                Ps[prow * 72 + tn * 16 + (l & 15)] = f2bf(sv[tn][r]);
            }
        __syncthreads();

        // O += P V  (A=P rows, B=V^T rows from Vs)
        #pragma unroll
        for (int ks = 0; ks < 2; ++ks) {
            const int prow = w * 16 + (l & 15);
            s16x8 pf = *(const s16x8*)(&Ps[prow * 72 + ks * 32 + (l >> 4) * 8]);
            #pragma unroll
            for (int td = 0; td < 4; ++td) {
                const int vrow = td * 16 + (l & 15);
                const int vch = (ks * 4 + (l >> 4)) ^ (vrow & 7);
                s16x8 vf = *(const s16x8*)(&Vs[vrow * 64 + vch * 8]);
                oacc[td] = __builtin_amdgcn_mfma_f32_16x16x32_bf16(pf, vf, oacc[td], 0, 0, 0);
            }
        }
        __syncthreads();
    }

    // epilogue: O/l + band rel-v term, store bf16 (b,t,c)
    float invl[4];
    #pragma unroll
    for (int r = 0; r < 4; ++r) invl[r] = 1.f / lsum[r];
    float ab[4][9];
    #pragma unroll
    for (int r = 0; r < 4; ++r) {
        const int iloc = w * 16 + (l >> 4) * 4 + r;
        #pragma unroll
        for (int rr = 0; rr < 9; ++rr)
            ab[r][rr] = __expf(sband[iloc * 9 + rr] - m[r]) * invl[r];
    }
    #pragma unroll
    for (int td = 0; td < 4; ++td) {
        const int d = td * 16 + (l & 15);
        const float* ev = emb_v + (size_t)h * 9 * 64 + d;
        #pragma unroll
        for (int r = 0; r < 4; ++r) {
            float v = oacc[td][r] * invl[r];
            #pragma unroll
            for (int rr = 0; rr < 9; ++rr) v += ab[r][rr] * ev[rr * 64];
            const int i = i0 + w * 16 + (l >> 4) * 4 + r;
            attT[((size_t)(b * T_ + i)) * C_ + h * 64 + d] = f2bf(v);
        }
    }
}

// ---------------------------------------------------------------------------
extern "C" void kernel_launch(void* const* d_in, const int* in_sizes, int n_in,
                              void* d_out, int out_size, void* d_ws, size_t ws_size,
                              hipStream_t stream) {
    const float* x    = (const float*)d_in[0];
    const float* c    = (const float*)d_in[1];
    const float* mask = (const float*)d_in[2];
    const float* wq   = (const float*)d_in[3];
    const float* bq   = (const float*)d_in[4];
    const float* wk   = (const float*)d_in[5];
    const float* bk   = (const float*)d_in[6];
    const float* wv   = (const float*)d_in[7];
    const float* bv   = (const float*)d_in[8];
    const float* wo   = (const float*)d_in[9];
    const float* bo   = (const float*)d_in[10];
    const float* ek   = (const float*)d_in[11];
    const float* ev   = (const float*)d_in[12];
    float* out = (float*)d_out;

    uint8_t* ws = (uint8_t*)d_ws;
    size_t off = 0;
    auto alloc = [&](size_t bytes) {
        uint8_t* p = ws + off;
        off += (bytes + 255) & ~(size_t)255;
        return p;
    };
    uint16_t* xT   = (uint16_t*)alloc((size_t)B_ * T_ * C_ * 2);
    uint16_t* cT   = (uint16_t*)alloc((size_t)B_ * T_ * C_ * 2);
    uint16_t* wb   = (uint16_t*)alloc((size_t)4 * C_ * C_ * 2);
    uint16_t* Qb   = (uint16_t*)alloc((size_t)B_ * T_ * C_ * 2);
    uint16_t* Kb   = (uint16_t*)alloc((size_t)B_ * T_ * C_ * 2);
    uint16_t* Vb   = (uint16_t*)alloc((size_t)B_ * C_ * T_ * 2);
    uint16_t* attT = (uint16_t*)alloc((size_t)B_ * T_ * C_ * 2);
    uint32_t* mbits = (uint32_t*)alloc((size_t)B_ * T_ * 32 * 4);

    transpose_bf16_kernel<<<dim3(768, B_, 2), 256, 0, stream>>>(x, c, xT, cT);
    convert_weights_kernel<<<dim3(576, 4), 256, 0, stream>>>(wq, wk, wv, wo, wb);
    mask_bits_kernel<<<dim3((B_ * T_ * T_) / 256), 256, 0, stream>>>(mask, mbits);
    gemm_kernel<false><<<dim3(48, 1, 12), 256, 0, stream>>>(xT, cT, wb, bq, bk, bv, bo,
                                                            attT, Qb, Kb, Vb, out);
    attn_kernel<<<dim3(T_ / 64, H_, B_), 256, 0, stream>>>(Qb, Kb, Vb, mbits, ek, ev, attT);
    gemm_kernel<true><<<dim3(48, 1, 4), 256, 0, stream>>>(xT, cT, wb, bq, bk, bv, bo,
                                                          attT, Qb, Kb, Vb, out);
}